// Round 5
// baseline (714.415 us; speedup 1.0000x reference)
//
#include <hip/hip_runtime.h>
#include <hip/hip_bf16.h>

// Problem constants (from reference)
#define D_IN    256
#define D_OUT   64
#define NNODES  50000
#define NEDGES  1250000

#define BUCK_SHIFT 8                       // 256 nodes per bucket
#define BUCK_NODES 256
#define NBUCK      196                     // ceil(50000/256)
#define CPAD       16                      // pad counters to 64B lines
#define EPB        4096                    // edges per binning block
#define NB_EDGE    ((NEDGES + EPB - 1) / EPB)   // 306

typedef float f32x4 __attribute__((ext_vector_type(4)));
typedef short s16x8 __attribute__((ext_vector_type(8)));   // 8 bf16 (4 VGPRs)

// fp32 -> bf16 bits, round-to-nearest-even
static __device__ __forceinline__ unsigned short f2bf(float f) {
    union { float f; unsigned u; } v; v.f = f;
    unsigned r = v.u + 0x7FFFu + ((v.u >> 16) & 1u);
    return (unsigned short)(r >> 16);
}
static __device__ __forceinline__ float bf2f(unsigned short b) {
    union { unsigned u; float f; } v; v.u = ((unsigned)b) << 16;
    return v.f;
}

// ---------------------------------------------------------------------------
// Kernel 1: h[N,64] = x[N,256] @ W[64,256]^T  via bf16 MFMA (fp32 accum).
// ---------------------------------------------------------------------------
__global__ __launch_bounds__(256) void gemm_h_mfma(
    const float* __restrict__ x, const float* __restrict__ W,
    unsigned short* __restrict__ h, int N)
{
    const int t    = threadIdx.x;
    const int wave = t >> 6;
    const int lane = t & 63;
    const int m    = lane & 15;
    const int q    = lane >> 4;
    const int rowA = blockIdx.x * 64 + wave * 16 + m;
    const int rowc = (rowA < N) ? rowA : (N - 1);

    const float* xr = x + (long long)rowc * D_IN + q * 8;

    f32x4 acc[4] = {};

    #pragma unroll
    for (int kb = 0; kb < 8; ++kb) {
        float4 a0 = *(const float4*)(xr + kb * 32);
        float4 a1 = *(const float4*)(xr + kb * 32 + 4);
        s16x8 af;
        af[0] = (short)f2bf(a0.x); af[1] = (short)f2bf(a0.y);
        af[2] = (short)f2bf(a0.z); af[3] = (short)f2bf(a0.w);
        af[4] = (short)f2bf(a1.x); af[5] = (short)f2bf(a1.y);
        af[6] = (short)f2bf(a1.z); af[7] = (short)f2bf(a1.w);

        #pragma unroll
        for (int c = 0; c < 4; ++c) {
            const float* wr = W + (c * 16 + m) * D_IN + kb * 32 + q * 8;
            float4 b0 = *(const float4*)wr;
            float4 b1 = *(const float4*)(wr + 4);
            s16x8 bf;
            bf[0] = (short)f2bf(b0.x); bf[1] = (short)f2bf(b0.y);
            bf[2] = (short)f2bf(b0.z); bf[3] = (short)f2bf(b0.w);
            bf[4] = (short)f2bf(b1.x); bf[5] = (short)f2bf(b1.y);
            bf[6] = (short)f2bf(b1.z); bf[7] = (short)f2bf(b1.w);
            acc[c] = __builtin_amdgcn_mfma_f32_16x16x32_bf16(af, bf, acc[c], 0, 0, 0);
        }
    }

    #pragma unroll
    for (int c = 0; c < 4; ++c) {
        #pragma unroll
        for (int r = 0; r < 4; ++r) {
            int gr = blockIdx.x * 64 + wave * 16 + q * 4 + r;
            if (gr < N)
                h[(long long)gr * D_OUT + c * 16 + m] = f2bf(acc[c][r]);
        }
    }
}

// ---------------------------------------------------------------------------
// Kernel 2: coarse histogram over 196 buckets. LDS-private, then one padded
// global atomic per (block, bucket) -> ~60K atomics over 196 separate lines.
// ---------------------------------------------------------------------------
__global__ __launch_bounds__(256) void coarse_hist(
    const int* __restrict__ dst, int* __restrict__ bcount)
{
    __shared__ int lh[NBUCK];
    int t = threadIdx.x;
    for (int i = t; i < NBUCK; i += 256) lh[i] = 0;
    __syncthreads();
    int base = blockIdx.x * EPB;
    int end  = min(base + EPB, NEDGES);
    for (int e = base + t; e < end; e += 256)
        atomicAdd(&lh[dst[e] >> BUCK_SHIFT], 1);
    __syncthreads();
    if (t < NBUCK) {
        int c = lh[t];
        if (c) atomicAdd(&bcount[t * CPAD], c);
    }
}

// ---------------------------------------------------------------------------
// Kernel 3: single-block exclusive scan of bucket counts -> bstart[NBUCK+1],
// and initialize padded bucket cursors.
// ---------------------------------------------------------------------------
__global__ __launch_bounds__(256) void bucket_scan(
    const int* __restrict__ bcount, int* __restrict__ bstart,
    int* __restrict__ bcursor)
{
    int t = threadIdx.x;
    int v = (t < NBUCK) ? bcount[t * CPAD] : 0;
    __shared__ int s[256];
    s[t] = v; __syncthreads();
    #pragma unroll
    for (int off = 1; off < 256; off <<= 1) {
        int u = (t >= off) ? s[t - off] : 0;
        __syncthreads();
        s[t] += u;
        __syncthreads();
    }
    if (t < NBUCK) {
        int st = s[t] - v;
        bstart[t] = st;
        bcursor[t * CPAD] = st;
    }
    if (t == 0) bstart[NBUCK] = NEDGES;
}

// ---------------------------------------------------------------------------
// Kernel 4: bin edges into bucket regions. Per block: LDS count, reserve a
// contiguous range per bucket (one padded atomic each), then scatter packed
// recs. Runs of ~21 recs/bucket/block -> lines mostly single-block ->
// write-back ~= useful bytes, not 64B per record.
// rec = [wt:32 | dst_local:8(hi16) | src:16(lo16)]
// ---------------------------------------------------------------------------
__global__ __launch_bounds__(256) void bin_edges(
    const int* __restrict__ src, const int* __restrict__ dst,
    const float* __restrict__ wt, int* __restrict__ bcursor,
    unsigned long long* __restrict__ brecs)
{
    __shared__ int lcnt[NBUCK];
    __shared__ int lbase[NBUCK];
    int t = threadIdx.x;
    for (int i = t; i < NBUCK; i += 256) lcnt[i] = 0;
    __syncthreads();

    int base = blockIdx.x * EPB;
    int end  = min(base + EPB, NEDGES);

    // phase 1: local bucket counts
    for (int e = base + t; e < end; e += 256)
        atomicAdd(&lcnt[dst[e] >> BUCK_SHIFT], 1);
    __syncthreads();

    // phase 2: reserve global ranges
    if (t < NBUCK) {
        int c = lcnt[t];
        lbase[t] = c ? atomicAdd(&bcursor[t * CPAD], c) : 0;
        lcnt[t]  = 0;   // reuse as local rank counter
    }
    __syncthreads();

    // phase 3: scatter packed records
    for (int e = base + t; e < end; e += 256) {
        int d = dst[e];
        int b = d >> BUCK_SHIFT;
        int r = atomicAdd(&lcnt[b], 1);
        unsigned lo = (unsigned)src[e] | ((unsigned)(d & (BUCK_NODES - 1)) << 16);
        unsigned long long rec = (unsigned long long)lo
                               | ((unsigned long long)__float_as_uint(wt[e]) << 32);
        brecs[lbase[b] + r] = rec;
    }
}

// ---------------------------------------------------------------------------
// Kernel 5: fused bucket aggregation. One block per bucket; 64KB LDS fp32
// accumulator [256 nodes][64 cols]. Waves take contiguous quarters of the
// bucket's recs; per rec: broadcast-read rec, coalesced 128B gather of h row,
// ds_add_f32 into LDS (2 lanes/bank = free). Epilogue adds bias and writes
// out contiguously.
// ---------------------------------------------------------------------------
__global__ __launch_bounds__(256) void agg_buckets(
    const unsigned long long* __restrict__ brecs, const int* __restrict__ bstart,
    const unsigned short* __restrict__ h, const float* __restrict__ bias,
    float* __restrict__ out)
{
    __shared__ float acc[BUCK_NODES * D_OUT];   // 65536 B
    int t = threadIdx.x;
    int b = blockIdx.x;
    int node0 = b << BUCK_SHIFT;
    int nn = min(BUCK_NODES, NNODES - node0);
    int span = nn * D_OUT;

    for (int i = t; i < span; i += 256) acc[i] = 0.0f;
    __syncthreads();

    int s0 = bstart[b];
    int e0 = bstart[b + 1];
    int cnt = e0 - s0;
    int wave = t >> 6, lane = t & 63;
    int per = (cnt + 3) >> 2;
    int i0 = s0 + wave * per;
    int i1 = min(i0 + per, e0);

    int i = i0;
    for (; i + 3 < i1; i += 4) {
        unsigned long long r0 = brecs[i + 0];
        unsigned long long r1 = brecs[i + 1];
        unsigned long long r2 = brecs[i + 2];
        unsigned long long r3 = brecs[i + 3];
        int  s0i = (int)(r0 & 0xFFFF), d0 = (int)((r0 >> 16) & 0xFF);
        int  s1i = (int)(r1 & 0xFFFF), d1 = (int)((r1 >> 16) & 0xFF);
        int  s2i = (int)(r2 & 0xFFFF), d2 = (int)((r2 >> 16) & 0xFF);
        int  s3i = (int)(r3 & 0xFFFF), d3 = (int)((r3 >> 16) & 0xFF);
        float v0 = bf2f(h[s0i * D_OUT + lane]);
        float v1 = bf2f(h[s1i * D_OUT + lane]);
        float v2 = bf2f(h[s2i * D_OUT + lane]);
        float v3 = bf2f(h[s3i * D_OUT + lane]);
        atomicAdd(&acc[d0 * D_OUT + lane], __uint_as_float((unsigned)(r0 >> 32)) * v0);
        atomicAdd(&acc[d1 * D_OUT + lane], __uint_as_float((unsigned)(r1 >> 32)) * v1);
        atomicAdd(&acc[d2 * D_OUT + lane], __uint_as_float((unsigned)(r2 >> 32)) * v2);
        atomicAdd(&acc[d3 * D_OUT + lane], __uint_as_float((unsigned)(r3 >> 32)) * v3);
    }
    for (; i < i1; ++i) {
        unsigned long long r = brecs[i];
        int si = (int)(r & 0xFFFF), d = (int)((r >> 16) & 0xFF);
        float v = bf2f(h[si * D_OUT + lane]);
        atomicAdd(&acc[d * D_OUT + lane], __uint_as_float((unsigned)(r >> 32)) * v);
    }
    __syncthreads();

    for (int i2 = t; i2 < span; i2 += 256)
        out[(long long)node0 * D_OUT + i2] = acc[i2] + bias[i2 & (D_OUT - 1)];
}

// ---------------------------------------------------------------------------
// Fallback path (ws too small): bias init + per-edge atomics
// ---------------------------------------------------------------------------
__global__ __launch_bounds__(256) void init_bias(
    float* __restrict__ out, const float* __restrict__ bias, int total)
{
    int i = blockIdx.x * blockDim.x + threadIdx.x;
    if (i < total) out[i] = bias[i & (D_OUT - 1)];
}

__global__ __launch_bounds__(256) void scatter_edges(
    const int* __restrict__ src, const int* __restrict__ dst,
    const float* __restrict__ wt, const unsigned short* __restrict__ h,
    float* __restrict__ out)
{
    long long gid = (long long)blockIdx.x * blockDim.x + threadIdx.x;
    int e    = (int)(gid >> 6);
    int lane = threadIdx.x & 63;
    if (e < NEDGES) {
        int   s = src[e];
        int   d = dst[e];
        float w = wt[e];
        float v = w * bf2f(h[(long long)s * D_OUT + lane]);
        atomicAdd(&out[(long long)d * D_OUT + lane], v);
    }
}

// ---------------------------------------------------------------------------
// Launch
// ---------------------------------------------------------------------------
extern "C" void kernel_launch(void* const* d_in, const int* in_sizes, int n_in,
                              void* d_out, int out_size, void* d_ws, size_t ws_size,
                              hipStream_t stream)
{
    const float* W     = (const float*)d_in[0];   // [64, 256]
    const float* bias  = (const float*)d_in[1];   // [64]
    const int*   edges = (const int*)  d_in[2];   // [2, E]
    const float* wt    = (const float*)d_in[3];   // [E]
    const float* x     = (const float*)d_in[4];   // [N, 256]
    float*       out   = (float*)d_out;           // [N, 64]

    const int* src = edges;
    const int* dst = edges + NEDGES;

    // workspace carve-up (bytes)
    char* ws = (char*)d_ws;
    const size_t OFF_H      = 0;                   // 6,400,000   (bf16 h)
    const size_t OFF_RECS   = 6400000;             // 10,000,000  (8B recs)
    const size_t OFF_BCOUNT = 16400000;            // 196*16*4 = 12,544
    const size_t OFF_BCUR   = 16412544;            // 12,544
    const size_t OFF_BSTART = 16425088;            // (196+1)*4 = 788
    const size_t REQUIRED   = 16425876;

    unsigned short* h = (unsigned short*)(ws + OFF_H);

    // 1) h = x @ W^T  (bf16 MFMA, bf16 out)
    gemm_h_mfma<<<(NNODES + 63) / 64, 256, 0, stream>>>(x, W, h, NNODES);

    if (ws_size >= REQUIRED) {
        unsigned long long* brecs   = (unsigned long long*)(ws + OFF_RECS);
        int*                bcount  = (int*)(ws + OFF_BCOUNT);
        int*                bcursor = (int*)(ws + OFF_BCUR);
        int*                bstart  = (int*)(ws + OFF_BSTART);

        hipMemsetAsync(bcount, 0, NBUCK * CPAD * sizeof(int), stream);

        coarse_hist<<<NB_EDGE, 256, 0, stream>>>(dst, bcount);
        bucket_scan<<<1, 256, 0, stream>>>(bcount, bstart, bcursor);
        bin_edges<<<NB_EDGE, 256, 0, stream>>>(src, dst, wt, bcursor, brecs);
        agg_buckets<<<NBUCK, 256, 0, stream>>>(brecs, bstart, h, bias, out);
    } else {
        int total = NNODES * D_OUT;
        init_bias<<<(total + 255) / 256, 256, 0, stream>>>(out, bias, total);
        long long threads = (long long)NEDGES * 64;
        int blocks = (int)((threads + 255) / 256);
        scatter_edges<<<blocks, 256, 0, stream>>>(src, dst, wt, h, out);
    }
}

// Round 6
// 228.326 us; speedup vs baseline: 3.1289x; 3.1289x over previous
//
#include <hip/hip_runtime.h>
#include <hip/hip_bf16.h>

// Problem constants (from reference)
#define D_IN    256
#define D_OUT   64
#define NNODES  50000
#define NEDGES  1250000

#define BUCK_SHIFT 8                       // 256 nodes per bucket
#define BUCK_NODES 256
#define NBUCK      196                     // ceil(50000/256)
#define CPAD       16                      // pad counters to 64B lines
#define EPB        4096                    // edges per binning block
#define NB_EDGE    ((NEDGES + EPB - 1) / EPB)   // 306

typedef float f32x4 __attribute__((ext_vector_type(4)));
typedef short s16x8 __attribute__((ext_vector_type(8)));   // 8 bf16 (4 VGPRs)

// fp32 -> bf16 bits, round-to-nearest-even
static __device__ __forceinline__ unsigned short f2bf(float f) {
    union { float f; unsigned u; } v; v.f = f;
    unsigned r = v.u + 0x7FFFu + ((v.u >> 16) & 1u);
    return (unsigned short)(r >> 16);
}
static __device__ __forceinline__ float bf2f(unsigned short b) {
    union { unsigned u; float f; } v; v.u = ((unsigned)b) << 16;
    return v.f;
}

// ---------------------------------------------------------------------------
// Kernel 1: h[N,64] = x[N,256] @ W[64,256]^T  via bf16 MFMA (fp32 accum).
// ---------------------------------------------------------------------------
__global__ __launch_bounds__(256) void gemm_h_mfma(
    const float* __restrict__ x, const float* __restrict__ W,
    unsigned short* __restrict__ h, int N)
{
    const int t    = threadIdx.x;
    const int wave = t >> 6;
    const int lane = t & 63;
    const int m    = lane & 15;
    const int q    = lane >> 4;
    const int rowA = blockIdx.x * 64 + wave * 16 + m;
    const int rowc = (rowA < N) ? rowA : (N - 1);

    const float* xr = x + (long long)rowc * D_IN + q * 8;

    f32x4 acc[4] = {};

    #pragma unroll
    for (int kb = 0; kb < 8; ++kb) {
        float4 a0 = *(const float4*)(xr + kb * 32);
        float4 a1 = *(const float4*)(xr + kb * 32 + 4);
        s16x8 af;
        af[0] = (short)f2bf(a0.x); af[1] = (short)f2bf(a0.y);
        af[2] = (short)f2bf(a0.z); af[3] = (short)f2bf(a0.w);
        af[4] = (short)f2bf(a1.x); af[5] = (short)f2bf(a1.y);
        af[6] = (short)f2bf(a1.z); af[7] = (short)f2bf(a1.w);

        #pragma unroll
        for (int c = 0; c < 4; ++c) {
            const float* wr = W + (c * 16 + m) * D_IN + kb * 32 + q * 8;
            float4 b0 = *(const float4*)wr;
            float4 b1 = *(const float4*)(wr + 4);
            s16x8 bf;
            bf[0] = (short)f2bf(b0.x); bf[1] = (short)f2bf(b0.y);
            bf[2] = (short)f2bf(b0.z); bf[3] = (short)f2bf(b0.w);
            bf[4] = (short)f2bf(b1.x); bf[5] = (short)f2bf(b1.y);
            bf[6] = (short)f2bf(b1.z); bf[7] = (short)f2bf(b1.w);
            acc[c] = __builtin_amdgcn_mfma_f32_16x16x32_bf16(af, bf, acc[c], 0, 0, 0);
        }
    }

    #pragma unroll
    for (int c = 0; c < 4; ++c) {
        #pragma unroll
        for (int r = 0; r < 4; ++r) {
            int gr = blockIdx.x * 64 + wave * 16 + q * 4 + r;
            if (gr < N)
                h[(long long)gr * D_OUT + c * 16 + m] = f2bf(acc[c][r]);
        }
    }
}

// ---------------------------------------------------------------------------
// Kernel 2: coarse histogram over 196 buckets (LDS-private, one padded
// global atomic per block-bucket).
// ---------------------------------------------------------------------------
__global__ __launch_bounds__(256) void coarse_hist(
    const int* __restrict__ dst, int* __restrict__ bcount)
{
    __shared__ int lh[NBUCK];
    int t = threadIdx.x;
    for (int i = t; i < NBUCK; i += 256) lh[i] = 0;
    __syncthreads();
    int base = blockIdx.x * EPB;
    int end  = min(base + EPB, NEDGES);
    for (int e = base + t; e < end; e += 256)
        atomicAdd(&lh[dst[e] >> BUCK_SHIFT], 1);
    __syncthreads();
    if (t < NBUCK) {
        int c = lh[t];
        if (c) atomicAdd(&bcount[t * CPAD], c);
    }
}

// ---------------------------------------------------------------------------
// Kernel 3: single-block scan of bucket counts -> bstart[NBUCK+1] + cursors.
// ---------------------------------------------------------------------------
__global__ __launch_bounds__(256) void bucket_scan(
    const int* __restrict__ bcount, int* __restrict__ bstart,
    int* __restrict__ bcursor)
{
    int t = threadIdx.x;
    int v = (t < NBUCK) ? bcount[t * CPAD] : 0;
    __shared__ int s[256];
    s[t] = v; __syncthreads();
    #pragma unroll
    for (int off = 1; off < 256; off <<= 1) {
        int u = (t >= off) ? s[t - off] : 0;
        __syncthreads();
        s[t] += u;
        __syncthreads();
    }
    if (t < NBUCK) {
        int st = s[t] - v;
        bstart[t] = st;
        bcursor[t * CPAD] = st;
    }
    if (t == 0) bstart[NBUCK] = NEDGES;
}

// ---------------------------------------------------------------------------
// Kernel 4: bin edges into bucket-grouped regions (runs of ~21 recs/bucket
// per block -> write lines mostly single-owner). Output = d_out scratch.
// rec = [wt:32 | dst_local:8 (bits16..23) | src:16 (lo)]
// ---------------------------------------------------------------------------
__global__ __launch_bounds__(256) void bin_edges(
    const int* __restrict__ src, const int* __restrict__ dst,
    const float* __restrict__ wt, int* __restrict__ bcursor,
    unsigned long long* __restrict__ binned)
{
    __shared__ int lcnt[NBUCK];
    __shared__ int lbase[NBUCK];
    int t = threadIdx.x;
    for (int i = t; i < NBUCK; i += 256) lcnt[i] = 0;
    __syncthreads();

    int base = blockIdx.x * EPB;
    int end  = min(base + EPB, NEDGES);

    for (int e = base + t; e < end; e += 256)
        atomicAdd(&lcnt[dst[e] >> BUCK_SHIFT], 1);
    __syncthreads();

    if (t < NBUCK) {
        int c = lcnt[t];
        lbase[t] = c ? atomicAdd(&bcursor[t * CPAD], c) : 0;
        lcnt[t]  = 0;   // reuse as local rank counter
    }
    __syncthreads();

    for (int e = base + t; e < end; e += 256) {
        int d = dst[e];
        int b = d >> BUCK_SHIFT;
        int r = atomicAdd(&lcnt[b], 1);
        unsigned lo = (unsigned)src[e] | ((unsigned)(d & (BUCK_NODES - 1)) << 16);
        unsigned long long rec = (unsigned long long)lo
                               | ((unsigned long long)__float_as_uint(wt[e]) << 32);
        binned[lbase[b] + r] = rec;
    }
}

// ---------------------------------------------------------------------------
// Kernel 5: per-bucket counting sort to per-node CSR. One block per bucket;
// streaming (no dependent-load chains): count 256 local nodes in LDS, scan,
// write starts/counts, scatter recs from binned (d_out) into csr (ws).
// Each block writes only its own contiguous ~51KB region.
// ---------------------------------------------------------------------------
__global__ __launch_bounds__(256) void sort_buckets(
    const unsigned long long* __restrict__ binned, const int* __restrict__ bstart,
    unsigned long long* __restrict__ csr,
    int* __restrict__ starts, int* __restrict__ counts)
{
    __shared__ int lcnt[BUCK_NODES];
    __shared__ int lcur[BUCK_NODES];
    __shared__ int s[256];
    int t = threadIdx.x;
    int b = blockIdx.x;
    int s0 = bstart[b];
    int e0 = bstart[b + 1];
    int node0 = b << BUCK_SHIFT;
    int nn = min(BUCK_NODES, NNODES - node0);

    lcnt[t] = 0;
    __syncthreads();

    for (int k = s0 + t; k < e0; k += 256)
        atomicAdd(&lcnt[(int)((binned[k] >> 16) & 0xFF)], 1);
    __syncthreads();

    int v = lcnt[t];
    s[t] = v; __syncthreads();
    #pragma unroll
    for (int off = 1; off < 256; off <<= 1) {
        int u = (t >= off) ? s[t - off] : 0;
        __syncthreads();
        s[t] += u;
        __syncthreads();
    }
    int excl = s[t] - v;
    lcur[t] = s0 + excl;          // absolute cursor within bucket region
    if (t < nn) {
        starts[node0 + t] = s0 + excl;
        counts[node0 + t] = v;
    }
    __syncthreads();

    for (int k = s0 + t; k < e0; k += 256) {
        unsigned long long r = binned[k];
        int dloc = (int)((r >> 16) & 0xFF);
        int pos  = atomicAdd(&lcur[dloc], 1);
        csr[pos] = r;
    }
}

// ---------------------------------------------------------------------------
// Kernel 6: aggregation. One wave per node, lane = output column, node in
// SGPR via readfirstlane (scalar starts/counts/rec loads); x4 unroll.
// ---------------------------------------------------------------------------
__global__ __launch_bounds__(256) void agg_nodes(
    const int2* __restrict__ recs, const int* __restrict__ starts,
    const int* __restrict__ counts, const unsigned short* __restrict__ h,
    const float* __restrict__ bias, float* __restrict__ out)
{
    int wid  = (blockIdx.x * 256 + threadIdx.x) >> 6;
    int node = __builtin_amdgcn_readfirstlane(wid);
    if (node >= NNODES) return;
    int lane = threadIdx.x & 63;

    float acc = bias[lane];
    int s0  = starts[node];
    int cnt = counts[node];
    int i = s0, e = s0 + cnt;

    for (; i + 3 < e; i += 4) {
        int2 r0 = recs[i + 0];
        int2 r1 = recs[i + 1];
        int2 r2 = recs[i + 2];
        int2 r3 = recs[i + 3];
        float v0 = bf2f(h[(r0.x & 0xFFFF) * D_OUT + lane]);
        float v1 = bf2f(h[(r1.x & 0xFFFF) * D_OUT + lane]);
        float v2 = bf2f(h[(r2.x & 0xFFFF) * D_OUT + lane]);
        float v3 = bf2f(h[(r3.x & 0xFFFF) * D_OUT + lane]);
        acc += __int_as_float(r0.y) * v0;
        acc += __int_as_float(r1.y) * v1;
        acc += __int_as_float(r2.y) * v2;
        acc += __int_as_float(r3.y) * v3;
    }
    for (; i < e; ++i) {
        int2 r = recs[i];
        acc += __int_as_float(r.y) * bf2f(h[(r.x & 0xFFFF) * D_OUT + lane]);
    }
    out[(long long)node * D_OUT + lane] = acc;
}

// ---------------------------------------------------------------------------
// Fallback path (ws too small): bias init + per-edge atomics
// ---------------------------------------------------------------------------
__global__ __launch_bounds__(256) void init_bias(
    float* __restrict__ out, const float* __restrict__ bias, int total)
{
    int i = blockIdx.x * blockDim.x + threadIdx.x;
    if (i < total) out[i] = bias[i & (D_OUT - 1)];
}

__global__ __launch_bounds__(256) void scatter_edges(
    const int* __restrict__ src, const int* __restrict__ dst,
    const float* __restrict__ wt, const unsigned short* __restrict__ h,
    float* __restrict__ out)
{
    long long gid = (long long)blockIdx.x * blockDim.x + threadIdx.x;
    int e    = (int)(gid >> 6);
    int lane = threadIdx.x & 63;
    if (e < NEDGES) {
        int   s = src[e];
        int   d = dst[e];
        float w = wt[e];
        float v = w * bf2f(h[(long long)s * D_OUT + lane]);
        atomicAdd(&out[(long long)d * D_OUT + lane], v);
    }
}

// ---------------------------------------------------------------------------
// Launch
// ---------------------------------------------------------------------------
extern "C" void kernel_launch(void* const* d_in, const int* in_sizes, int n_in,
                              void* d_out, int out_size, void* d_ws, size_t ws_size,
                              hipStream_t stream)
{
    const float* W     = (const float*)d_in[0];   // [64, 256]
    const float* bias  = (const float*)d_in[1];   // [64]
    const int*   edges = (const int*)  d_in[2];   // [2, E]
    const float* wt    = (const float*)d_in[3];   // [E]
    const float* x     = (const float*)d_in[4];   // [N, 256]
    float*       out   = (float*)d_out;           // [N, 64]

    const int* src = edges;
    const int* dst = edges + NEDGES;

    // workspace carve-up (bytes)
    char* ws = (char*)d_ws;
    const size_t OFF_H      = 0;                   // 6,400,000   (bf16 h)
    const size_t OFF_RECS   = 6400000;             // 10,000,000  (CSR recs)
    const size_t OFF_STARTS = 16400000;            // 200,000
    const size_t OFF_COUNTS = 16600000;            // 200,000
    const size_t OFF_BCOUNT = 16800000;            // 12,544
    const size_t OFF_BCUR   = 16812544;            // 12,544
    const size_t OFF_BSTART = 16825088;            // 788
    const size_t REQUIRED   = 16825876;

    unsigned short* h = (unsigned short*)(ws + OFF_H);

    // 1) h = x @ W^T  (bf16 MFMA, bf16 out)
    gemm_h_mfma<<<(NNODES + 63) / 64, 256, 0, stream>>>(x, W, h, NNODES);

    if (ws_size >= REQUIRED) {
        unsigned long long* csr     = (unsigned long long*)(ws + OFF_RECS);
        int*                starts  = (int*)(ws + OFF_STARTS);
        int*                counts  = (int*)(ws + OFF_COUNTS);
        int*                bcount  = (int*)(ws + OFF_BCOUNT);
        int*                bcursor = (int*)(ws + OFF_BCUR);
        int*                bstart  = (int*)(ws + OFF_BSTART);

        // d_out doubles as scratch for bucket-binned recs (10 MB <= 12.8 MB);
        // agg_nodes fully overwrites it afterwards.
        unsigned long long* binned = (unsigned long long*)d_out;

        hipMemsetAsync(bcount, 0, NBUCK * CPAD * sizeof(int), stream);

        coarse_hist<<<NB_EDGE, 256, 0, stream>>>(dst, bcount);
        bucket_scan<<<1, 256, 0, stream>>>(bcount, bstart, bcursor);
        bin_edges<<<NB_EDGE, 256, 0, stream>>>(src, dst, wt, bcursor, binned);
        sort_buckets<<<NBUCK, 256, 0, stream>>>(binned, bstart, csr, starts, counts);

        int nb = (NNODES * 64 + 255) / 256;  // 12500 blocks, 4 nodes/block
        agg_nodes<<<nb, 256, 0, stream>>>((const int2*)csr, starts, counts, h, bias, out);
    } else {
        int total = NNODES * D_OUT;
        init_bias<<<(total + 255) / 256, 256, 0, stream>>>(out, bias, total);
        long long threads = (long long)NEDGES * 64;
        int blocks = (int)((threads + 255) / 256);
        scatter_edges<<<blocks, 256, 0, stream>>>(src, dst, wt, h, out);
    }
}

// Round 7
// 207.617 us; speedup vs baseline: 3.4410x; 1.0997x over previous
//
#include <hip/hip_runtime.h>
#include <hip/hip_bf16.h>

// Problem constants (from reference)
#define D_IN    256
#define D_OUT   64
#define NNODES  50000
#define NEDGES  1250000

#define BUCK_SHIFT 8                       // 256 nodes per bucket
#define BUCK_NODES 256
#define NBUCK      196                     // ceil(50000/256)
#define CPAD       16                      // pad counters to 64B lines
#define EPB        4096                    // edges per binning block
#define NB_EDGE    ((NEDGES + EPB - 1) / EPB)   // 306

typedef float f32x4 __attribute__((ext_vector_type(4)));
typedef short s16x8 __attribute__((ext_vector_type(8)));   // 8 bf16 (4 VGPRs)

// fp32 -> bf16 bits, round-to-nearest-even
static __device__ __forceinline__ unsigned short f2bf(float f) {
    union { float f; unsigned u; } v; v.f = f;
    unsigned r = v.u + 0x7FFFu + ((v.u >> 16) & 1u);
    return (unsigned short)(r >> 16);
}
static __device__ __forceinline__ float bf2f(unsigned short b) {
    union { unsigned u; float f; } v; v.u = ((unsigned)b) << 16;
    return v.f;
}

// ---------------------------------------------------------------------------
// Kernel 0: one-time W fp32 -> bf16 (64x256 = 16K elements)
// ---------------------------------------------------------------------------
__global__ __launch_bounds__(256) void convert_w(
    const float* __restrict__ W, unsigned short* __restrict__ Wb)
{
    int i = blockIdx.x * 256 + threadIdx.x;
    if (i < D_OUT * D_IN) Wb[i] = f2bf(W[i]);
}

// ---------------------------------------------------------------------------
// Kernel 1: h[N,64] = x[N,256] @ W[64,256]^T  via bf16 MFMA (fp32 accum).
// W staged in LDS pre-swizzled into MFMA B-fragment order:
//   slot(c,kb,lane) = (c*8+kb)*64 + lane  (uint4 = 8 bf16 per slot)
// -> inner-loop ds_read_b128 is lane-contiguous (conflict-free), and NO
// per-iteration B conversion (was 32 f2bf per MFMA in v1).
// Per kb: 2 global dwordx4 (x) + 8 f2bf + 4 ds_read_b128 + 4 MFMA.
// ---------------------------------------------------------------------------
__global__ __launch_bounds__(256) void gemm_h_mfma(
    const float* __restrict__ x, const unsigned short* __restrict__ Wb,
    unsigned short* __restrict__ h, int N)
{
    __shared__ uint4 sW[2048];   // 32 KB: 4 c * 8 kb * 64 lanes

    const int t    = threadIdx.x;
    const int lane = t & 63;
    const int wave = t >> 6;
    const int m    = lane & 15;
    const int q    = lane >> 4;

    // stage W fragments (gather from L2-resident 32 KB, store linear)
    #pragma unroll
    for (int i = 0; i < 8; ++i) {
        int slot = t + i * 256;
        int ln   = slot & 63;
        int kb   = (slot >> 6) & 7;
        int c    = slot >> 9;
        int lm = ln & 15, lq = ln >> 4;
        sW[slot] = ((const uint4*)Wb)[(c * 16 + lm) * 32 + kb * 4 + lq];
    }
    __syncthreads();

    const int rowA = blockIdx.x * 64 + wave * 16 + m;
    const int rowc = (rowA < N) ? rowA : (N - 1);
    const float* xr = x + (long long)rowc * D_IN + q * 8;

    f32x4 acc[4] = {};

    #pragma unroll
    for (int kb = 0; kb < 8; ++kb) {
        float4 a0 = *(const float4*)(xr + kb * 32);
        float4 a1 = *(const float4*)(xr + kb * 32 + 4);
        s16x8 af;
        af[0] = (short)f2bf(a0.x); af[1] = (short)f2bf(a0.y);
        af[2] = (short)f2bf(a0.z); af[3] = (short)f2bf(a0.w);
        af[4] = (short)f2bf(a1.x); af[5] = (short)f2bf(a1.y);
        af[6] = (short)f2bf(a1.z); af[7] = (short)f2bf(a1.w);

        #pragma unroll
        for (int c = 0; c < 4; ++c) {
            s16x8 bf = *(const s16x8*)&sW[(c * 8 + kb) * 64 + lane];
            acc[c] = __builtin_amdgcn_mfma_f32_16x16x32_bf16(af, bf, acc[c], 0, 0, 0);
        }
    }

    // C/D: col = c*16 + m, row = blk*64 + wave*16 + q*4 + r
    #pragma unroll
    for (int c = 0; c < 4; ++c) {
        #pragma unroll
        for (int r = 0; r < 4; ++r) {
            int gr = blockIdx.x * 64 + wave * 16 + q * 4 + r;
            if (gr < N)
                h[(long long)gr * D_OUT + c * 16 + m] = f2bf(acc[c][r]);
        }
    }
}

// ---------------------------------------------------------------------------
// Kernel 2: coarse histogram over 196 buckets (LDS-private, one padded
// global atomic per block-bucket).
// ---------------------------------------------------------------------------
__global__ __launch_bounds__(256) void coarse_hist(
    const int* __restrict__ dst, int* __restrict__ bcount)
{
    __shared__ int lh[NBUCK];
    int t = threadIdx.x;
    for (int i = t; i < NBUCK; i += 256) lh[i] = 0;
    __syncthreads();
    int base = blockIdx.x * EPB;
    int end  = min(base + EPB, NEDGES);
    for (int e = base + t; e < end; e += 256)
        atomicAdd(&lh[dst[e] >> BUCK_SHIFT], 1);
    __syncthreads();
    if (t < NBUCK) {
        int c = lh[t];
        if (c) atomicAdd(&bcount[t * CPAD], c);
    }
}

// ---------------------------------------------------------------------------
// Kernel 3: single-block scan of bucket counts -> bstart[NBUCK+1] + cursors.
// ---------------------------------------------------------------------------
__global__ __launch_bounds__(256) void bucket_scan(
    const int* __restrict__ bcount, int* __restrict__ bstart,
    int* __restrict__ bcursor)
{
    int t = threadIdx.x;
    int v = (t < NBUCK) ? bcount[t * CPAD] : 0;
    __shared__ int s[256];
    s[t] = v; __syncthreads();
    #pragma unroll
    for (int off = 1; off < 256; off <<= 1) {
        int u = (t >= off) ? s[t - off] : 0;
        __syncthreads();
        s[t] += u;
        __syncthreads();
    }
    if (t < NBUCK) {
        int st = s[t] - v;
        bstart[t] = st;
        bcursor[t * CPAD] = st;
    }
    if (t == 0) bstart[NBUCK] = NEDGES;
}

// ---------------------------------------------------------------------------
// Kernel 4: bin edges into bucket-grouped regions (runs of ~21 recs/bucket
// per block -> write lines mostly single-owner). Output = d_out scratch.
// rec = [wt:32 | dst_local:8 (bits16..23) | src:16 (lo)]
// ---------------------------------------------------------------------------
__global__ __launch_bounds__(256) void bin_edges(
    const int* __restrict__ src, const int* __restrict__ dst,
    const float* __restrict__ wt, int* __restrict__ bcursor,
    unsigned long long* __restrict__ binned)
{
    __shared__ int lcnt[NBUCK];
    __shared__ int lbase[NBUCK];
    int t = threadIdx.x;
    for (int i = t; i < NBUCK; i += 256) lcnt[i] = 0;
    __syncthreads();

    int base = blockIdx.x * EPB;
    int end  = min(base + EPB, NEDGES);

    for (int e = base + t; e < end; e += 256)
        atomicAdd(&lcnt[dst[e] >> BUCK_SHIFT], 1);
    __syncthreads();

    if (t < NBUCK) {
        int c = lcnt[t];
        lbase[t] = c ? atomicAdd(&bcursor[t * CPAD], c) : 0;
        lcnt[t]  = 0;   // reuse as local rank counter
    }
    __syncthreads();

    for (int e = base + t; e < end; e += 256) {
        int d = dst[e];
        int b = d >> BUCK_SHIFT;
        int r = atomicAdd(&lcnt[b], 1);
        unsigned lo = (unsigned)src[e] | ((unsigned)(d & (BUCK_NODES - 1)) << 16);
        unsigned long long rec = (unsigned long long)lo
                               | ((unsigned long long)__float_as_uint(wt[e]) << 32);
        binned[lbase[b] + r] = rec;
    }
}

// ---------------------------------------------------------------------------
// Kernel 5: per-bucket counting sort to per-node CSR. One block per bucket;
// streaming: count 256 local nodes in LDS, scan, write starts/counts,
// scatter recs from binned (d_out) into csr (ws).
// ---------------------------------------------------------------------------
__global__ __launch_bounds__(256) void sort_buckets(
    const unsigned long long* __restrict__ binned, const int* __restrict__ bstart,
    unsigned long long* __restrict__ csr,
    int* __restrict__ starts, int* __restrict__ counts)
{
    __shared__ int lcnt[BUCK_NODES];
    __shared__ int lcur[BUCK_NODES];
    __shared__ int s[256];
    int t = threadIdx.x;
    int b = blockIdx.x;
    int s0 = bstart[b];
    int e0 = bstart[b + 1];
    int node0 = b << BUCK_SHIFT;
    int nn = min(BUCK_NODES, NNODES - node0);

    lcnt[t] = 0;
    __syncthreads();

    for (int k = s0 + t; k < e0; k += 256)
        atomicAdd(&lcnt[(int)((binned[k] >> 16) & 0xFF)], 1);
    __syncthreads();

    int v = lcnt[t];
    s[t] = v; __syncthreads();
    #pragma unroll
    for (int off = 1; off < 256; off <<= 1) {
        int u = (t >= off) ? s[t - off] : 0;
        __syncthreads();
        s[t] += u;
        __syncthreads();
    }
    int excl = s[t] - v;
    lcur[t] = s0 + excl;          // absolute cursor within bucket region
    if (t < nn) {
        starts[node0 + t] = s0 + excl;
        counts[node0 + t] = v;
    }
    __syncthreads();

    for (int k = s0 + t; k < e0; k += 256) {
        unsigned long long r = binned[k];
        int dloc = (int)((r >> 16) & 0xFF);
        int pos  = atomicAdd(&lcur[dloc], 1);
        csr[pos] = r;
    }
}

// ---------------------------------------------------------------------------
// Kernel 6: aggregation. One wave per node, lane = output column, node in
// SGPR via readfirstlane (scalar starts/counts/rec loads); x4 unroll.
// ---------------------------------------------------------------------------
__global__ __launch_bounds__(256) void agg_nodes(
    const int2* __restrict__ recs, const int* __restrict__ starts,
    const int* __restrict__ counts, const unsigned short* __restrict__ h,
    const float* __restrict__ bias, float* __restrict__ out)
{
    int wid  = (blockIdx.x * 256 + threadIdx.x) >> 6;
    int node = __builtin_amdgcn_readfirstlane(wid);
    if (node >= NNODES) return;
    int lane = threadIdx.x & 63;

    float acc = bias[lane];
    int s0  = starts[node];
    int cnt = counts[node];
    int i = s0, e = s0 + cnt;

    for (; i + 3 < e; i += 4) {
        int2 r0 = recs[i + 0];
        int2 r1 = recs[i + 1];
        int2 r2 = recs[i + 2];
        int2 r3 = recs[i + 3];
        float v0 = bf2f(h[(r0.x & 0xFFFF) * D_OUT + lane]);
        float v1 = bf2f(h[(r1.x & 0xFFFF) * D_OUT + lane]);
        float v2 = bf2f(h[(r2.x & 0xFFFF) * D_OUT + lane]);
        float v3 = bf2f(h[(r3.x & 0xFFFF) * D_OUT + lane]);
        acc += __int_as_float(r0.y) * v0;
        acc += __int_as_float(r1.y) * v1;
        acc += __int_as_float(r2.y) * v2;
        acc += __int_as_float(r3.y) * v3;
    }
    for (; i < e; ++i) {
        int2 r = recs[i];
        acc += __int_as_float(r.y) * bf2f(h[(r.x & 0xFFFF) * D_OUT + lane]);
    }
    out[(long long)node * D_OUT + lane] = acc;
}

// ---------------------------------------------------------------------------
// Fallback path (ws too small): bias init + per-edge atomics
// ---------------------------------------------------------------------------
__global__ __launch_bounds__(256) void init_bias(
    float* __restrict__ out, const float* __restrict__ bias, int total)
{
    int i = blockIdx.x * blockDim.x + threadIdx.x;
    if (i < total) out[i] = bias[i & (D_OUT - 1)];
}

__global__ __launch_bounds__(256) void scatter_edges(
    const int* __restrict__ src, const int* __restrict__ dst,
    const float* __restrict__ wt, const unsigned short* __restrict__ h,
    float* __restrict__ out)
{
    long long gid = (long long)blockIdx.x * blockDim.x + threadIdx.x;
    int e    = (int)(gid >> 6);
    int lane = threadIdx.x & 63;
    if (e < NEDGES) {
        int   s = src[e];
        int   d = dst[e];
        float w = wt[e];
        float v = w * bf2f(h[(long long)s * D_OUT + lane]);
        atomicAdd(&out[(long long)d * D_OUT + lane], v);
    }
}

// ---------------------------------------------------------------------------
// Launch
// ---------------------------------------------------------------------------
extern "C" void kernel_launch(void* const* d_in, const int* in_sizes, int n_in,
                              void* d_out, int out_size, void* d_ws, size_t ws_size,
                              hipStream_t stream)
{
    const float* W     = (const float*)d_in[0];   // [64, 256]
    const float* bias  = (const float*)d_in[1];   // [64]
    const int*   edges = (const int*)  d_in[2];   // [2, E]
    const float* wt    = (const float*)d_in[3];   // [E]
    const float* x     = (const float*)d_in[4];   // [N, 256]
    float*       out   = (float*)d_out;           // [N, 64]

    const int* src = edges;
    const int* dst = edges + NEDGES;

    // workspace carve-up (bytes)
    char* ws = (char*)d_ws;
    const size_t OFF_H      = 0;                   // 6,400,000   (bf16 h)
    const size_t OFF_WB     = 6400000;             // 32,768     (bf16 W)
    const size_t OFF_RECS   = 6432768;             // 10,000,000 (CSR recs)
    const size_t OFF_STARTS = 16432768;            // 200,000
    const size_t OFF_COUNTS = 16632768;            // 200,000
    const size_t OFF_BCOUNT = 16832768;            // 12,544
    const size_t OFF_BCUR   = 16845312;            // 12,544
    const size_t OFF_BSTART = 16857856;            // 788
    const size_t REQUIRED   = 16858644;

    unsigned short* h  = (unsigned short*)(ws + OFF_H);
    unsigned short* Wb = (unsigned short*)(ws + OFF_WB);

    // 0) W -> bf16 (one-time, 16K elems)
    convert_w<<<(D_OUT * D_IN + 255) / 256, 256, 0, stream>>>(W, Wb);

    // 1) h = x @ W^T  (bf16 MFMA, LDS fragment-order W, bf16 out)
    gemm_h_mfma<<<(NNODES + 63) / 64, 256, 0, stream>>>(x, Wb, h, NNODES);

    if (ws_size >= REQUIRED) {
        unsigned long long* csr     = (unsigned long long*)(ws + OFF_RECS);
        int*                starts  = (int*)(ws + OFF_STARTS);
        int*                counts  = (int*)(ws + OFF_COUNTS);
        int*                bcount  = (int*)(ws + OFF_BCOUNT);
        int*                bcursor = (int*)(ws + OFF_BCUR);
        int*                bstart  = (int*)(ws + OFF_BSTART);

        // d_out doubles as scratch for bucket-binned recs (10 MB <= 12.8 MB);
        // agg_nodes fully overwrites it afterwards.
        unsigned long long* binned = (unsigned long long*)d_out;

        hipMemsetAsync(bcount, 0, NBUCK * CPAD * sizeof(int), stream);

        coarse_hist<<<NB_EDGE, 256, 0, stream>>>(dst, bcount);
        bucket_scan<<<1, 256, 0, stream>>>(bcount, bstart, bcursor);
        bin_edges<<<NB_EDGE, 256, 0, stream>>>(src, dst, wt, bcursor, binned);
        sort_buckets<<<NBUCK, 256, 0, stream>>>(binned, bstart, csr, starts, counts);

        int nb = (NNODES * 64 + 255) / 256;  // 12500 blocks, 4 nodes/block
        agg_nodes<<<nb, 256, 0, stream>>>((const int2*)csr, starts, counts, h, bias, out);
    } else {
        int total = NNODES * D_OUT;
        init_bias<<<(total + 255) / 256, 256, 0, stream>>>(out, bias, total);
        long long threads = (long long)NEDGES * 64;
        int blocks = (int)((threads + 255) / 256);
        scatter_edges<<<blocks, 256, 0, stream>>>(src, dst, wt, h, out);
    }
}